// Round 1
// baseline (462.861 us; speedup 1.0000x reference)
//
#include <hip/hip_runtime.h>

typedef __attribute__((ext_vector_type(8))) short short8;
typedef __attribute__((ext_vector_type(4))) float f32x4;
typedef __attribute__((ext_vector_type(4))) unsigned short ushort4v;

#define LOG2E 1.4426950408889634f
#define ATTN_SCALE 0.125f   /* 1/sqrt(64) exactly */

__device__ __forceinline__ unsigned short f2bf(float f) {
    union { float f; unsigned int u; } v; v.f = f;
    unsigned int r = v.u + 0x7FFFu + ((v.u >> 16) & 1u);
    return (unsigned short)(r >> 16);
}

// ---------------- fp32 -> bf16 elementwise ----------------
__global__ __launch_bounds__(256) void cvt_bf16(const float* __restrict__ in,
                                                unsigned short* __restrict__ out, int n) {
    int i = (blockIdx.x * 256 + threadIdx.x) * 4;
    if (i >= n) return;
    f32x4 v = *(const f32x4*)(in + i);
    ushort4v o;
    o[0] = f2bf(v[0]); o[1] = f2bf(v[1]); o[2] = f2bf(v[2]); o[3] = f2bf(v[3]);
    *(ushort4v*)(out + i) = o;
}

// ---------------- transpose + convert: W[K][N] -> WT[N][K] bf16 ----------------
__global__ __launch_bounds__(256) void transpose_cvt(const float* __restrict__ W,
                                                     unsigned short* __restrict__ WT,
                                                     int Kd, int Nd) {
    __shared__ float tile[32][33];
    int n0 = blockIdx.x * 32, k0 = blockIdx.y * 32;
    int tx = threadIdx.x, ty = threadIdx.y;
    #pragma unroll
    for (int i = 0; i < 4; ++i)
        tile[ty + i * 8][tx] = W[(size_t)(k0 + ty + i * 8) * Nd + n0 + tx];
    __syncthreads();
    #pragma unroll
    for (int i = 0; i < 4; ++i) {
        int r = ty + i * 8;
        WT[(size_t)(n0 + r) * Kd + k0 + tx] = f2bf(tile[tx][r]);
    }
}

// ---------------- GEMM: C[M][N] = A[M][K] * BT[N][K]^T  (m97 structure) ----------------
#define AS1U(p) ((const __attribute__((address_space(1))) unsigned int*)(p))
#define AS3U(p) ((__attribute__((address_space(3))) unsigned int*)(p))

template<int BIAS, int OUTBF16>
__global__ __launch_bounds__(256) void gemm_bt(const unsigned short* __restrict__ A,
                                               const unsigned short* __restrict__ BT,
                                               void* __restrict__ Cv,
                                               const float* __restrict__ bias,
                                               int M, int N, int K) {
    __shared__ unsigned short As[128 * 32];
    __shared__ unsigned short Bs[128 * 32];
    int tid = threadIdx.x;
    int l = tid & 63, l15 = l & 15, l4 = l >> 4;
    int w = tid >> 6, wm = w >> 1, wn = w & 1;
    int bm = blockIdx.x, bn = blockIdx.y;

    f32x4 acc[4][4];
    #pragma unroll
    for (int mt = 0; mt < 4; ++mt)
        #pragma unroll
        for (int nt = 0; nt < 4; ++nt)
            acc[mt][nt] = (f32x4){0.f, 0.f, 0.f, 0.f};

    int srow = tid >> 2;             // 0..63
    int skk  = (tid & 3) * 8;        // 8-elem chunk within 32-wide K slab

    const unsigned short* Ab = A  + (size_t)(bm * 128) * K;
    const unsigned short* Bb = BT + (size_t)(bn * 128) * K;

    for (int kt = 0; kt < K; kt += 32) {
        __syncthreads();
        __builtin_amdgcn_global_load_lds(AS1U(Ab + (size_t)srow        * K + kt + skk), AS3U(&As[tid * 8]),         16, 0, 0);
        __builtin_amdgcn_global_load_lds(AS1U(Ab + (size_t)(srow + 64) * K + kt + skk), AS3U(&As[(256 + tid) * 8]), 16, 0, 0);
        __builtin_amdgcn_global_load_lds(AS1U(Bb + (size_t)srow        * K + kt + skk), AS3U(&Bs[tid * 8]),         16, 0, 0);
        __builtin_amdgcn_global_load_lds(AS1U(Bb + (size_t)(srow + 64) * K + kt + skk), AS3U(&Bs[(256 + tid) * 8]), 16, 0, 0);
        __syncthreads();

        short8 av[4], bv[4];
        #pragma unroll
        for (int mt = 0; mt < 4; ++mt)
            av[mt] = *(const short8*)&As[(wm * 64 + mt * 16 + l15) * 32 + l4 * 8];
        #pragma unroll
        for (int nt = 0; nt < 4; ++nt)
            bv[nt] = *(const short8*)&Bs[(wn * 64 + nt * 16 + l15) * 32 + l4 * 8];
        #pragma unroll
        for (int mt = 0; mt < 4; ++mt)
            #pragma unroll
            for (int nt = 0; nt < 4; ++nt)
                acc[mt][nt] = __builtin_amdgcn_mfma_f32_16x16x32_bf16(av[mt], bv[nt], acc[mt][nt], 0, 0, 0);
    }

    #pragma unroll
    for (int mt = 0; mt < 4; ++mt) {
        #pragma unroll
        for (int r = 0; r < 4; ++r) {
            int row = bm * 128 + wm * 64 + mt * 16 + l4 * 4 + r;
            #pragma unroll
            for (int nt = 0; nt < 4; ++nt) {
                int col = bn * 128 + wn * 64 + nt * 16 + l15;
                float vv = acc[mt][nt][r];
                if (BIAS) vv += bias[col];
                if (OUTBF16) ((unsigned short*)Cv)[(size_t)row * N + col] = f2bf(vv);
                else         ((float*)Cv)[(size_t)row * N + col] = vv;
            }
        }
    }
}

// ---------------- flash attention (causal) ----------------
// qkv: [B*T][3072] bf16 rows (q|k|v each 1024, head h at h*64)
// ao : [B*T][1024] bf16
__device__ __forceinline__ int swz64(int row, int e) {
    return row * 64 + (e ^ ((row & 7) << 3));     // XOR-swizzle 8-elem chunks in a 128B row
}

__global__ __launch_bounds__(256) void flash_attn(const unsigned short* __restrict__ qkv,
                                                  unsigned short* __restrict__ ao) {
    int qt = blockIdx.x;              // 0..31 : 64-row q tile
    int bh = blockIdx.y;              // 0..63
    int b = bh >> 4, h = bh & 15;
    int tid = threadIdx.x;
    int w = tid >> 6, l = tid & 63, l15 = l & 15, l4 = l >> 4;

    __shared__ unsigned short Ks[64 * 64];
    __shared__ unsigned short Vt[64 * 64];
    __shared__ unsigned short Ps[4][16 * 80];

    const size_t base = (size_t)b * 2048 * 3072;

    // Q fragments (A-operand): lane holds Q[q0 + l15][l4*8 .. +7] for each 32-wide k-step
    int qrow = qt * 64 + w * 16 + l15;
    const unsigned short* qp = qkv + base + (size_t)qrow * 3072 + h * 64 + l4 * 8;
    short8 qa0 = *(const short8*)(qp);
    short8 qa1 = *(const short8*)(qp + 32);

    float m[4], ll[4];
    f32x4 oacc[4];
    #pragma unroll
    for (int r = 0; r < 4; ++r) { m[r] = -__builtin_inff(); ll[r] = 0.f; }
    #pragma unroll
    for (int dt = 0; dt < 4; ++dt) oacc[dt] = (f32x4){0.f, 0.f, 0.f, 0.f};

    int r_ = tid >> 2;               // staging row 0..63
    int c0 = (tid & 3) * 16;         // staging col chunk

    for (int kvb = 0; kvb <= qt; ++kvb) {
        __syncthreads();
        {   // stage K (swizzled rows) and V^T (swizzled rows of d)
            int krow = kvb * 64 + r_;
            const unsigned short* kp = qkv + base + (size_t)krow * 3072 + 1024 + h * 64 + c0;
            *(short8*)&Ks[swz64(r_, c0)]     = *(const short8*)kp;
            *(short8*)&Ks[swz64(r_, c0 + 8)] = *(const short8*)(kp + 8);
            const unsigned short* vp = qkv + base + (size_t)krow * 3072 + 2048 + h * 64 + c0;
            short8 v0 = *(const short8*)vp;
            short8 v1 = *(const short8*)(vp + 8);
            #pragma unroll
            for (int c = 0; c < 8; ++c) {
                int row0 = c0 + c, row1 = c0 + 8 + c;
                Vt[row0 * 64 + (r_ ^ ((row0 & 7) << 3))] = (unsigned short)v0[c];
                Vt[row1 * 64 + (r_ ^ ((row1 & 7) << 3))] = (unsigned short)v1[c];
            }
        }
        __syncthreads();

        // S = Q K^T for this wave's 16 q-rows x 64 kv
        f32x4 sacc[4];
        #pragma unroll
        for (int kvt = 0; kvt < 4; ++kvt) {
            sacc[kvt] = (f32x4){0.f, 0.f, 0.f, 0.f};
            short8 k0v = *(const short8*)&Ks[swz64(kvt * 16 + l15, l4 * 8)];
            short8 k1v = *(const short8*)&Ks[swz64(kvt * 16 + l15, 32 + l4 * 8)];
            sacc[kvt] = __builtin_amdgcn_mfma_f32_16x16x32_bf16(qa0, k0v, sacc[kvt], 0, 0, 0);
            sacc[kvt] = __builtin_amdgcn_mfma_f32_16x16x32_bf16(qa1, k1v, sacc[kvt], 0, 0, 0);
        }

        bool diag = (kvb == qt);
        #pragma unroll
        for (int kvt = 0; kvt < 4; ++kvt)
            #pragma unroll
            for (int r = 0; r < 4; ++r) {
                float s = sacc[kvt][r] * ATTN_SCALE;
                if (diag) {
                    int ql = w * 16 + l4 * 4 + r;
                    int kl = kvt * 16 + l15;
                    if (kl > ql) s = -__builtin_inff();
                }
                sacc[kvt][r] = s;
            }

        // online softmax per q-row (rows live across the 16-lane l15 group)
        #pragma unroll
        for (int r = 0; r < 4; ++r) {
            float t = fmaxf(fmaxf(sacc[0][r], sacc[1][r]), fmaxf(sacc[2][r], sacc[3][r]));
            t = fmaxf(t, __shfl_xor(t, 1));
            t = fmaxf(t, __shfl_xor(t, 2));
            t = fmaxf(t, __shfl_xor(t, 4));
            t = fmaxf(t, __shfl_xor(t, 8));
            float mn = fmaxf(m[r], t);
            float alpha = exp2f((m[r] - mn) * LOG2E);
            float rsum = 0.f;
            #pragma unroll
            for (int kvt = 0; kvt < 4; ++kvt) {
                float p = exp2f((sacc[kvt][r] - mn) * LOG2E);
                sacc[kvt][r] = p;
                rsum += p;
            }
            rsum += __shfl_xor(rsum, 1);
            rsum += __shfl_xor(rsum, 2);
            rsum += __shfl_xor(rsum, 4);
            rsum += __shfl_xor(rsum, 8);
            ll[r] = ll[r] * alpha + rsum;
            m[r] = mn;
            #pragma unroll
            for (int dt = 0; dt < 4; ++dt) oacc[dt][r] *= alpha;
        }

        // P (f32, D-layout) -> per-wave LDS -> A-operand fragments
        #pragma unroll
        for (int kvt = 0; kvt < 4; ++kvt)
            #pragma unroll
            for (int r = 0; r < 4; ++r)
                Ps[w][(l4 * 4 + r) * 80 + kvt * 16 + l15] = f2bf(sacc[kvt][r]);
        // same-wave DS ops are in-order: no barrier needed
        short8 pa0 = *(const short8*)&Ps[w][l15 * 80 + l4 * 8];
        short8 pa1 = *(const short8*)&Ps[w][l15 * 80 + 32 + l4 * 8];

        #pragma unroll
        for (int dt = 0; dt < 4; ++dt) {
            short8 vb0 = *(const short8*)&Vt[swz64(dt * 16 + l15, l4 * 8)];
            short8 vb1 = *(const short8*)&Vt[swz64(dt * 16 + l15, 32 + l4 * 8)];
            oacc[dt] = __builtin_amdgcn_mfma_f32_16x16x32_bf16(pa0, vb0, oacc[dt], 0, 0, 0);
            oacc[dt] = __builtin_amdgcn_mfma_f32_16x16x32_bf16(pa1, vb1, oacc[dt], 0, 0, 0);
        }
    }

    #pragma unroll
    for (int r = 0; r < 4; ++r) {
        float inv = 1.0f / ll[r];
        int row = qt * 64 + w * 16 + l4 * 4 + r;
        unsigned short* op = ao + ((size_t)b * 2048 + row) * 1024 + h * 64;
        #pragma unroll
        for (int dt = 0; dt < 4; ++dt)
            op[dt * 16 + l15] = f2bf(oacc[dt][r] * inv);
    }
}

// ---------------- launch ----------------
extern "C" void kernel_launch(void* const* d_in, const int* in_sizes, int n_in,
                              void* d_out, int out_size, void* d_ws, size_t ws_size,
                              hipStream_t stream) {
    const float* x    = (const float*)d_in[0];
    // d_in[1] = causal mask (deterministic tril) — applied analytically
    const float* Wqkv = (const float*)d_in[2];
    const float* Wo   = (const float*)d_in[3];
    const float* bo   = (const float*)d_in[4];
    float* out = (float*)d_out;

    char* ws = (char*)d_ws;
    unsigned short* xb    = (unsigned short*)(ws);               // [8192][1024] bf16
    unsigned short* wqkvt = (unsigned short*)(ws + 16777216);    // [3072][1024] bf16 (Wqkv^T)
    unsigned short* wot   = (unsigned short*)(ws + 23068672);    // [1024][1024] bf16 (Wo^T)
    unsigned short* qkvb  = (unsigned short*)(ws + 25165824);    // [8192][3072] bf16
    unsigned short* ao    = (unsigned short*)(ws + 75497472);    // [8192][1024] bf16

    cvt_bf16<<<8192, 256, 0, stream>>>(x, xb, 8192 * 1024);
    transpose_cvt<<<dim3(96, 32), dim3(32, 8), 0, stream>>>(Wqkv, wqkvt, 1024, 3072);
    transpose_cvt<<<dim3(32, 32), dim3(32, 8), 0, stream>>>(Wo, wot, 1024, 1024);

    gemm_bt<0, 1><<<dim3(64, 24), 256, 0, stream>>>(xb, wqkvt, (void*)qkvb, nullptr, 8192, 3072, 1024);
    flash_attn<<<dim3(32, 64), 256, 0, stream>>>(qkvb, ao);
    gemm_bt<1, 0><<<dim3(64, 8), 256, 0, stream>>>(ao, wot, (void*)out, bo, 8192, 1024, 1024);
}

// Round 3
// 406.841 us; speedup vs baseline: 1.1377x; 1.1377x over previous
//
#include <hip/hip_runtime.h>

typedef __attribute__((ext_vector_type(8))) short short8;
typedef __attribute__((ext_vector_type(4))) float f32x4;
typedef __attribute__((ext_vector_type(4))) unsigned short ushort4v;

#define LOG2E 1.4426950408889634f
#define ATTN_SCALE 0.125f   /* 1/sqrt(64) exactly */

__device__ __forceinline__ unsigned short f2bf(float f) {
    union { float f; unsigned int u; } v; v.f = f;
    unsigned int r = v.u + 0x7FFFu + ((v.u >> 16) & 1u);
    return (unsigned short)(r >> 16);
}

// ---------------- fp32 -> bf16 elementwise ----------------
__global__ __launch_bounds__(256) void cvt_bf16(const float* __restrict__ in,
                                                unsigned short* __restrict__ out, int n) {
    int i = (blockIdx.x * 256 + threadIdx.x) * 4;
    if (i >= n) return;
    f32x4 v = *(const f32x4*)(in + i);
    ushort4v o;
    o[0] = f2bf(v[0]); o[1] = f2bf(v[1]); o[2] = f2bf(v[2]); o[3] = f2bf(v[3]);
    *(ushort4v*)(out + i) = o;
}

// ---------------- transpose + convert: W[K][N] -> WT[N][K] bf16 ----------------
__global__ __launch_bounds__(256) void transpose_cvt(const float* __restrict__ W,
                                                     unsigned short* __restrict__ WT,
                                                     int Kd, int Nd) {
    __shared__ float tile[32][33];
    int n0 = blockIdx.x * 32, k0 = blockIdx.y * 32;
    int tx = threadIdx.x, ty = threadIdx.y;
    #pragma unroll
    for (int i = 0; i < 4; ++i)
        tile[ty + i * 8][tx] = W[(size_t)(k0 + ty + i * 8) * Nd + n0 + tx];
    __syncthreads();
    #pragma unroll
    for (int i = 0; i < 4; ++i) {
        int r = ty + i * 8;
        WT[(size_t)(n0 + r) * Kd + k0 + tx] = f2bf(tile[tx][r]);
    }
}

// ---------------- GEMM: C[M][N] = A[M][K] * BT[N][K]^T  (m97 structure) ----------------
#define AS1U(p) ((const __attribute__((address_space(1))) unsigned int*)(p))
#define AS3U(p) ((__attribute__((address_space(3))) unsigned int*)(p))

template<int BIAS, int OUTBF16>
__global__ __launch_bounds__(256) void gemm_bt(const unsigned short* __restrict__ A,
                                               const unsigned short* __restrict__ BT,
                                               void* __restrict__ Cv,
                                               const float* __restrict__ bias,
                                               int M, int N, int K) {
    __shared__ unsigned short As[128 * 32];
    __shared__ unsigned short Bs[128 * 32];
    int tid = threadIdx.x;
    int l = tid & 63, l15 = l & 15, l4 = l >> 4;
    int w = tid >> 6, wm = w >> 1, wn = w & 1;
    int bm = blockIdx.x, bn = blockIdx.y;

    f32x4 acc[4][4];
    #pragma unroll
    for (int mt = 0; mt < 4; ++mt)
        #pragma unroll
        for (int nt = 0; nt < 4; ++nt)
            acc[mt][nt] = (f32x4){0.f, 0.f, 0.f, 0.f};

    int srow = tid >> 2;             // 0..63
    int skk  = (tid & 3) * 8;        // 8-elem chunk within 32-wide K slab

    const unsigned short* Ab = A  + (size_t)(bm * 128) * K;
    const unsigned short* Bb = BT + (size_t)(bn * 128) * K;

    for (int kt = 0; kt < K; kt += 32) {
        __syncthreads();
        __builtin_amdgcn_global_load_lds(AS1U(Ab + (size_t)srow        * K + kt + skk), AS3U(&As[tid * 8]),         16, 0, 0);
        __builtin_amdgcn_global_load_lds(AS1U(Ab + (size_t)(srow + 64) * K + kt + skk), AS3U(&As[(256 + tid) * 8]), 16, 0, 0);
        __builtin_amdgcn_global_load_lds(AS1U(Bb + (size_t)srow        * K + kt + skk), AS3U(&Bs[tid * 8]),         16, 0, 0);
        __builtin_amdgcn_global_load_lds(AS1U(Bb + (size_t)(srow + 64) * K + kt + skk), AS3U(&Bs[(256 + tid) * 8]), 16, 0, 0);
        __syncthreads();

        short8 av[4], bv[4];
        #pragma unroll
        for (int mt = 0; mt < 4; ++mt)
            av[mt] = *(const short8*)&As[(wm * 64 + mt * 16 + l15) * 32 + l4 * 8];
        #pragma unroll
        for (int nt = 0; nt < 4; ++nt)
            bv[nt] = *(const short8*)&Bs[(wn * 64 + nt * 16 + l15) * 32 + l4 * 8];
        #pragma unroll
        for (int mt = 0; mt < 4; ++mt)
            #pragma unroll
            for (int nt = 0; nt < 4; ++nt)
                acc[mt][nt] = __builtin_amdgcn_mfma_f32_16x16x32_bf16(av[mt], bv[nt], acc[mt][nt], 0, 0, 0);
    }

    #pragma unroll
    for (int mt = 0; mt < 4; ++mt) {
        #pragma unroll
        for (int r = 0; r < 4; ++r) {
            int row = bm * 128 + wm * 64 + mt * 16 + l4 * 4 + r;
            #pragma unroll
            for (int nt = 0; nt < 4; ++nt) {
                int col = bn * 128 + wn * 64 + nt * 16 + l15;
                float vv = acc[mt][nt][r];
                if (BIAS) vv += bias[col];
                if (OUTBF16) ((unsigned short*)Cv)[(size_t)row * N + col] = f2bf(vv);
                else         ((float*)Cv)[(size_t)row * N + col] = vv;
            }
        }
    }
}

// ---------------- flash attention (causal) ----------------
// qk: [B*T][2048] bf16 (q|k each 1024, head h at h*64)
// vt: [1024][B*T]  bf16 (V pre-transposed: row = h*64+d, col = b*2048+t)
// ao: [B*T][1024] bf16
__device__ __forceinline__ int swz64(int row, int e) {
    return row * 64 + (e ^ ((row & 7) << 3));     // XOR-swizzle 8-elem chunks in a 128B row
}

__global__ __launch_bounds__(256) void flash_attn(const unsigned short* __restrict__ qk,
                                                  const unsigned short* __restrict__ vt,
                                                  unsigned short* __restrict__ ao) {
    int pr = blockIdx.x;              // 0..15 : pairs q-tiles (pr, 31-pr) -> uniform 33 iters
    int bh = blockIdx.y;              // 0..63
    int b = bh >> 4, h = bh & 15;
    int tid = threadIdx.x;
    int w = tid >> 6, l = tid & 63, l15 = l & 15, l4 = l >> 4;

    __shared__ unsigned short Ks[4096];   // K tile  [kv=64][d=64]  swizzled
    __shared__ unsigned short Vs[4096];   // V^T tile [d=64][kv=64] swizzled
    __shared__ unsigned short Ps[4096];   // per-wave P [16][64]    swizzled

    const size_t qkbase = (size_t)b * 2048 * 2048;

    // global_load_lds staging: wave w writes chunks w*128 + j*64 + lane (16B each).
    // LDS dest is linear (wave-uniform base + lane*16); global source is
    // pre-swizzled per-lane so the LDS image matches swz64 layout.
    int c0i = w * 128 + l;
    int row0 = c0i >> 3, sub0 = c0i & 7;
    int c1i = c0i + 64;
    int row1 = c1i >> 3, sub1 = c1i & 7;

    const unsigned short* Kp0b = qk + qkbase + 1024 + h * 64 + (size_t)row0 * 2048 + 8 * (sub0 ^ (row0 & 7));
    const unsigned short* Kp1b = qk + qkbase + 1024 + h * 64 + (size_t)row1 * 2048 + 8 * (sub1 ^ (row1 & 7));
    const unsigned short* Vp0b = vt + (size_t)(h * 64 + row0) * 8192 + (size_t)b * 2048 + 8 * (sub0 ^ (row0 & 7));
    const unsigned short* Vp1b = vt + (size_t)(h * 64 + row1) * 8192 + (size_t)b * 2048 + 8 * (sub1 ^ (row1 & 7));

    unsigned short* Kd0 = &Ks[w * 1024];
    unsigned short* Kd1 = &Ks[w * 1024 + 512];
    unsigned short* Vd0 = &Vs[w * 1024];
    unsigned short* Vd1 = &Vs[w * 1024 + 512];

    #pragma unroll
    for (int t = 0; t < 2; ++t) {
        int qt = t ? (31 - pr) : pr;

        int qrow = qt * 64 + w * 16 + l15;
        const unsigned short* qp = qk + qkbase + (size_t)qrow * 2048 + h * 64 + l4 * 8;
        short8 qa0 = *(const short8*)(qp);
        short8 qa1 = *(const short8*)(qp + 32);

        float m[4], ll[4];
        f32x4 oacc[4];
        #pragma unroll
        for (int r = 0; r < 4; ++r) { m[r] = -__builtin_inff(); ll[r] = 0.f; }
        #pragma unroll
        for (int dt = 0; dt < 4; ++dt) oacc[dt] = (f32x4){0.f, 0.f, 0.f, 0.f};

        const unsigned short* kp0 = Kp0b;
        const unsigned short* kp1 = Kp1b;
        const unsigned short* vp0 = Vp0b;
        const unsigned short* vp1 = Vp1b;

        for (int kvb = 0; kvb <= qt; ++kvb) {
            __syncthreads();   // prior iter's LDS reads done before overwrite
            __builtin_amdgcn_global_load_lds(AS1U(kp0), AS3U(Kd0), 16, 0, 0);
            __builtin_amdgcn_global_load_lds(AS1U(kp1), AS3U(Kd1), 16, 0, 0);
            __builtin_amdgcn_global_load_lds(AS1U(vp0), AS3U(Vd0), 16, 0, 0);
            __builtin_amdgcn_global_load_lds(AS1U(vp1), AS3U(Vd1), 16, 0, 0);
            kp0 += 64 * 2048; kp1 += 64 * 2048; vp0 += 64; vp1 += 64;
            __syncthreads();   // drains vmcnt (compiler emits vmcnt(0) before s_barrier)

            // S = Q K^T : this wave's 16 q-rows x 64 kv
            f32x4 sacc[4];
            __builtin_amdgcn_s_setprio(1);
            #pragma unroll
            for (int kvt = 0; kvt < 4; ++kvt) {
                short8 k0v = *(const short8*)&Ks[swz64(kvt * 16 + l15, l4 * 8)];
                short8 k1v = *(const short8*)&Ks[swz64(kvt * 16 + l15, 32 + l4 * 8)];
                sacc[kvt] = (f32x4){0.f, 0.f, 0.f, 0.f};
                sacc[kvt] = __builtin_amdgcn_mfma_f32_16x16x32_bf16(qa0, k0v, sacc[kvt], 0, 0, 0);
                sacc[kvt] = __builtin_amdgcn_mfma_f32_16x16x32_bf16(qa1, k1v, sacc[kvt], 0, 0, 0);
            }
            __builtin_amdgcn_s_setprio(0);

            bool diag = (kvb == qt);
            #pragma unroll
            for (int kvt = 0; kvt < 4; ++kvt)
                #pragma unroll
                for (int r = 0; r < 4; ++r) {
                    float s = sacc[kvt][r] * ATTN_SCALE;
                    if (diag) {
                        int ql = w * 16 + l4 * 4 + r;
                        int kl = kvt * 16 + l15;
                        if (kl > ql) s = -__builtin_inff();
                    }
                    sacc[kvt][r] = s;
                }

            // online softmax per q-row (row lives across the 16-lane l15 group),
            // with defer-max (T13, THR=8): skip O-rescale when max growth small.
            #pragma unroll
            for (int r = 0; r < 4; ++r) {
                float tmax = fmaxf(fmaxf(sacc[0][r], sacc[1][r]), fmaxf(sacc[2][r], sacc[3][r]));
                tmax = fmaxf(tmax, __shfl_xor(tmax, 1));
                tmax = fmaxf(tmax, __shfl_xor(tmax, 2));
                tmax = fmaxf(tmax, __shfl_xor(tmax, 4));
                tmax = fmaxf(tmax, __shfl_xor(tmax, 8));
                bool skip = (tmax <= m[r] + 8.f);          // uniform within 16-lane group
                float mn = skip ? m[r] : tmax;
                float rsum = 0.f;
                #pragma unroll
                for (int kvt = 0; kvt < 4; ++kvt) {
                    float p = exp2f((sacc[kvt][r] - mn) * LOG2E);
                    sacc[kvt][r] = p;
                    rsum += p;
                }
                rsum += __shfl_xor(rsum, 1);
                rsum += __shfl_xor(rsum, 2);
                rsum += __shfl_xor(rsum, 4);
                rsum += __shfl_xor(rsum, 8);
                if (skip) {
                    ll[r] += rsum;
                } else {
                    float alpha = exp2f((m[r] - mn) * LOG2E);
                    ll[r] = ll[r] * alpha + rsum;
                    m[r] = mn;
                    #pragma unroll
                    for (int dt = 0; dt < 4; ++dt) oacc[dt][r] *= alpha;
                }
            }

            // P -> per-wave LDS (swizzled, conflict-light) -> A-operand fragments
            #pragma unroll
            for (int kvt = 0; kvt < 4; ++kvt)
                #pragma unroll
                for (int r = 0; r < 4; ++r)
                    Ps[w * 1024 + swz64(l4 * 4 + r, kvt * 16 + l15)] = f2bf(sacc[kvt][r]);
            // same-wave DS ordering: compiler inserts lgkmcnt before dependent reads
            short8 pa0 = *(const short8*)&Ps[w * 1024 + swz64(l15, l4 * 8)];
            short8 pa1 = *(const short8*)&Ps[w * 1024 + swz64(l15, 32 + l4 * 8)];

            __builtin_amdgcn_s_setprio(1);
            #pragma unroll
            for (int dt = 0; dt < 4; ++dt) {
                short8 vb0 = *(const short8*)&Vs[swz64(dt * 16 + l15, l4 * 8)];
                short8 vb1 = *(const short8*)&Vs[swz64(dt * 16 + l15, 32 + l4 * 8)];
                oacc[dt] = __builtin_amdgcn_mfma_f32_16x16x32_bf16(pa0, vb0, oacc[dt], 0, 0, 0);
                oacc[dt] = __builtin_amdgcn_mfma_f32_16x16x32_bf16(pa1, vb1, oacc[dt], 0, 0, 0);
            }
            __builtin_amdgcn_s_setprio(0);
        }

        #pragma unroll
        for (int r = 0; r < 4; ++r) {
            float inv = 1.0f / ll[r];
            int row = qt * 64 + w * 16 + l4 * 4 + r;
            unsigned short* op = ao + ((size_t)b * 2048 + row) * 1024 + h * 64;
            #pragma unroll
            for (int dt = 0; dt < 4; ++dt)
                op[dt * 16 + l15] = f2bf(oacc[dt][r] * inv);
        }
    }
}

// ---------------- launch ----------------
extern "C" void kernel_launch(void* const* d_in, const int* in_sizes, int n_in,
                              void* d_out, int out_size, void* d_ws, size_t ws_size,
                              hipStream_t stream) {
    const float* x    = (const float*)d_in[0];
    // d_in[1] = causal mask (deterministic tril) — applied analytically
    const float* Wqkv = (const float*)d_in[2];
    const float* Wo   = (const float*)d_in[3];
    const float* bo   = (const float*)d_in[4];
    float* out = (float*)d_out;

    char* ws = (char*)d_ws;
    unsigned short* xb    = (unsigned short*)(ws);               // [8192][1024] bf16, 16 MB
    unsigned short* wqkvt = (unsigned short*)(ws + 16777216);    // [3072][1024] bf16 (Wqkv^T), 6 MB
    unsigned short* wot   = (unsigned short*)(ws + 23068672);    // [1024][1024] bf16 (Wo^T), 2 MB
    unsigned short* qkb   = (unsigned short*)(ws + 25165824);    // [8192][2048] bf16 (q|k), 32 MB
    unsigned short* vtb   = (unsigned short*)(ws + 58720256);    // [1024][8192] bf16 (V^T), 16 MB
    unsigned short* ao    = (unsigned short*)(ws + 75497472);    // [8192][1024] bf16, 16 MB

    cvt_bf16<<<8192, 256, 0, stream>>>(x, xb, 8192 * 1024);
    transpose_cvt<<<dim3(96, 32), dim3(32, 8), 0, stream>>>(Wqkv, wqkvt, 1024, 3072);
    transpose_cvt<<<dim3(32, 32), dim3(32, 8), 0, stream>>>(Wo, wot, 1024, 1024);

    // QK projection: [8192][2048]
    gemm_bt<0, 1><<<dim3(64, 16), 256, 0, stream>>>(xb, wqkvt, (void*)qkb, nullptr, 8192, 2048, 1024);
    // V^T projection: vt[d_global][token] = sum_k WqkvT[2048+d][k] * x[token][k]
    gemm_bt<0, 1><<<dim3(8, 64), 256, 0, stream>>>(wqkvt + (size_t)2048 * 1024, xb, (void*)vtb, nullptr, 1024, 8192, 1024);

    flash_attn<<<dim3(16, 64), 256, 0, stream>>>(qkb, vtb, ao);

    gemm_bt<1, 0><<<dim3(64, 8), 256, 0, stream>>>(ao, wot, (void*)out, bo, 8192, 1024, 1024);
}

// Round 8
// 395.659 us; speedup vs baseline: 1.1698x; 1.0283x over previous
//
#include <hip/hip_runtime.h>

typedef __attribute__((ext_vector_type(8))) short short8;
typedef __attribute__((ext_vector_type(4))) float f32x4;
typedef __attribute__((ext_vector_type(4))) unsigned short ushort4v;

#define QK_PRESCALE 0.18033688011112043f   /* 0.125 * log2(e): S comes out in exp2 domain */
#define DEFER_THR 11.5f                    /* ~8 nats in exp2 domain */

__device__ __forceinline__ unsigned short f2bf(float f) {
    union { float f; unsigned int u; } v; v.f = f;
    unsigned int r = v.u + 0x7FFFu + ((v.u >> 16) & 1u);
    return (unsigned short)(r >> 16);
}

// ---------------- fp32 -> bf16 elementwise ----------------
__global__ __launch_bounds__(256) void cvt_bf16(const float* __restrict__ in,
                                                unsigned short* __restrict__ out, int n) {
    int i = (blockIdx.x * 256 + threadIdx.x) * 4;
    if (i >= n) return;
    f32x4 v = *(const f32x4*)(in + i);
    ushort4v o;
    o[0] = f2bf(v[0]); o[1] = f2bf(v[1]); o[2] = f2bf(v[2]); o[3] = f2bf(v[3]);
    *(ushort4v*)(out + i) = o;
}

// ---------------- transpose + convert: W[K][N] -> WT[N][K] bf16 ----------------
__global__ __launch_bounds__(256) void transpose_cvt(const float* __restrict__ W,
                                                     unsigned short* __restrict__ WT,
                                                     int Kd, int Nd) {
    __shared__ float tile[32][33];
    int n0 = blockIdx.x * 32, k0 = blockIdx.y * 32;
    int tx = threadIdx.x, ty = threadIdx.y;
    #pragma unroll
    for (int i = 0; i < 4; ++i)
        tile[ty + i * 8][tx] = W[(size_t)(k0 + ty + i * 8) * Nd + n0 + tx];
    __syncthreads();
    #pragma unroll
    for (int i = 0; i < 4; ++i) {
        int r = ty + i * 8;
        WT[(size_t)(n0 + r) * Kd + k0 + tx] = f2bf(tile[tx][r]);
    }
}

// ---------------- GEMM: C[M][N] = A[M][K] * BT[N][K]^T  (m97 structure) ----------------
#define AS1U(p) ((const __attribute__((address_space(1))) unsigned int*)(p))
#define AS3U(p) ((__attribute__((address_space(3))) unsigned int*)(p))

template<int BIAS, int OUTBF16, int QSCALE>
__global__ __launch_bounds__(256) void gemm_bt(const unsigned short* __restrict__ A,
                                               const unsigned short* __restrict__ BT,
                                               void* __restrict__ Cv,
                                               const float* __restrict__ bias,
                                               int M, int N, int K) {
    __shared__ unsigned short As[128 * 32];
    __shared__ unsigned short Bs[128 * 32];
    int tid = threadIdx.x;
    int l = tid & 63, l15 = l & 15, l4 = l >> 4;
    int w = tid >> 6, wm = w >> 1, wn = w & 1;
    int bm = blockIdx.x, bn = blockIdx.y;

    f32x4 acc[4][4];
    #pragma unroll
    for (int mt = 0; mt < 4; ++mt)
        #pragma unroll
        for (int nt = 0; nt < 4; ++nt)
            acc[mt][nt] = (f32x4){0.f, 0.f, 0.f, 0.f};

    int srow = tid >> 2;             // 0..63
    int skk  = (tid & 3) * 8;        // 8-elem chunk within 32-wide K slab

    const unsigned short* Ab = A  + (size_t)(bm * 128) * K;
    const unsigned short* Bb = BT + (size_t)(bn * 128) * K;

    for (int kt = 0; kt < K; kt += 32) {
        __syncthreads();
        __builtin_amdgcn_global_load_lds(AS1U(Ab + (size_t)srow        * K + kt + skk), AS3U(&As[tid * 8]),         16, 0, 0);
        __builtin_amdgcn_global_load_lds(AS1U(Ab + (size_t)(srow + 64) * K + kt + skk), AS3U(&As[(256 + tid) * 8]), 16, 0, 0);
        __builtin_amdgcn_global_load_lds(AS1U(Bb + (size_t)srow        * K + kt + skk), AS3U(&Bs[tid * 8]),         16, 0, 0);
        __builtin_amdgcn_global_load_lds(AS1U(Bb + (size_t)(srow + 64) * K + kt + skk), AS3U(&Bs[(256 + tid) * 8]), 16, 0, 0);
        __syncthreads();

        short8 av[4], bv[4];
        #pragma unroll
        for (int mt = 0; mt < 4; ++mt)
            av[mt] = *(const short8*)&As[(wm * 64 + mt * 16 + l15) * 32 + l4 * 8];
        #pragma unroll
        for (int nt = 0; nt < 4; ++nt)
            bv[nt] = *(const short8*)&Bs[(wn * 64 + nt * 16 + l15) * 32 + l4 * 8];
        #pragma unroll
        for (int mt = 0; mt < 4; ++mt)
            #pragma unroll
            for (int nt = 0; nt < 4; ++nt)
                acc[mt][nt] = __builtin_amdgcn_mfma_f32_16x16x32_bf16(av[mt], bv[nt], acc[mt][nt], 0, 0, 0);
    }

    #pragma unroll
    for (int mt = 0; mt < 4; ++mt) {
        #pragma unroll
        for (int r = 0; r < 4; ++r) {
            int row = bm * 128 + wm * 64 + mt * 16 + l4 * 4 + r;
            #pragma unroll
            for (int nt = 0; nt < 4; ++nt) {
                int col = bn * 128 + wn * 64 + nt * 16 + l15;
                float vv = acc[mt][nt][r];
                if (BIAS) vv += bias[col];
                if (QSCALE && col < 1024) vv *= QK_PRESCALE;   // q columns only
                if (OUTBF16) ((unsigned short*)Cv)[(size_t)row * N + col] = f2bf(vv);
                else         ((float*)Cv)[(size_t)row * N + col] = vv;
            }
        }
    }
}

// ---------------- flash attention (causal) ----------------
// qk: [B*T][2048] bf16 (q|k each 1024, head h at h*64; q pre-scaled by 0.125*log2e)
// vt: [1024][B*T]  bf16 (V pre-transposed: row = h*64+d, col = b*2048+t)
// ao: [B*T][1024] bf16
__device__ __forceinline__ int swz64(int row, int e) {
    return row * 64 + (e ^ ((row & 7) << 3));     // XOR-swizzle 8-elem chunks in a 128B row
}

__global__ __launch_bounds__(256) void flash_attn(const unsigned short* __restrict__ qk,
                                                  const unsigned short* __restrict__ vt,
                                                  unsigned short* __restrict__ ao) {
    // XCD-aware bijective remap (nwg=1024, 8 XCDs, cpx=128): each XCD owns 8
    // consecutive bh values -> that XCD's L2 holds their K/V (8 * 512KB = 4MB).
    int nid = (blockIdx.x & 7) * 128 + (blockIdx.x >> 3);
    int pr = nid & 15;                // pairs q-tiles (pr, 31-pr): uniform 33 iters
    int bh = nid >> 4;                // 0..63
    int b = bh >> 4, h = bh & 15;
    int tid = threadIdx.x;
    int w = tid >> 6, l = tid & 63, l15 = l & 15, l4 = l >> 4;

    __shared__ unsigned short Ks[2][4096];   // K tile  [kv=64][d=64]  swizzled, dbuf
    __shared__ unsigned short Vs[2][4096];   // V^T tile [d=64][kv=64] swizzled, dbuf
    __shared__ unsigned short Ps[4096];      // per-wave P [16][64]    swizzled

    const size_t qkbase = (size_t)b * 2048 * 2048;

    // Staging geometry: wave w writes chunks w*128 + j*64 + lane (16B each).
    // LDS dest linear (wave-uniform base + lane*16); global source pre-swizzled
    // per-lane so the LDS image matches swz64 layout.
    int c0i = w * 128 + l;
    int row0 = c0i >> 3, sub0 = c0i & 7;
    int c1i = c0i + 64;
    int row1 = c1i >> 3, sub1 = c1i & 7;

    const unsigned short* Kp0b = qk + qkbase + 1024 + h * 64 + (size_t)row0 * 2048 + 8 * (sub0 ^ (row0 & 7));
    const unsigned short* Kp1b = qk + qkbase + 1024 + h * 64 + (size_t)row1 * 2048 + 8 * (sub1 ^ (row1 & 7));
    const unsigned short* Vp0b = vt + (size_t)(h * 64 + row0) * 8192 + (size_t)b * 2048 + 8 * (sub0 ^ (row0 & 7));
    const unsigned short* Vp1b = vt + (size_t)(h * 64 + row1) * 8192 + (size_t)b * 2048 + 8 * (sub1 ^ (row1 & 7));

    #define STAGE(buf, kvb_)                                                                        \
        do {                                                                                        \
            size_t koff = (size_t)(kvb_) * (64 * 2048);                                             \
            int    voff = (kvb_) * 64;                                                              \
            __builtin_amdgcn_global_load_lds(AS1U(Kp0b + koff), AS3U(&Ks[buf][w * 1024]),       16, 0, 0); \
            __builtin_amdgcn_global_load_lds(AS1U(Kp1b + koff), AS3U(&Ks[buf][w * 1024 + 512]), 16, 0, 0); \
            __builtin_amdgcn_global_load_lds(AS1U(Vp0b + voff), AS3U(&Vs[buf][w * 1024]),       16, 0, 0); \
            __builtin_amdgcn_global_load_lds(AS1U(Vp1b + voff), AS3U(&Vs[buf][w * 1024 + 512]), 16, 0, 0); \
        } while (0)

    #pragma unroll
    for (int t = 0; t < 2; ++t) {
        int qt = t ? (31 - pr) : pr;

        int qrow = qt * 64 + w * 16 + l15;
        const unsigned short* qp = qk + qkbase + (size_t)qrow * 2048 + h * 64 + l4 * 8;
        short8 qa0 = *(const short8*)(qp);
        short8 qa1 = *(const short8*)(qp + 32);

        float m[4], ll[4];
        f32x4 oacc[4];
        #pragma unroll
        for (int r = 0; r < 4; ++r) { m[r] = -__builtin_inff(); ll[r] = 0.f; }
        #pragma unroll
        for (int dt = 0; dt < 4; ++dt) oacc[dt] = (f32x4){0.f, 0.f, 0.f, 0.f};

        STAGE(0, 0);
        __syncthreads();           // drain prologue loads (vmcnt(0) before s_barrier)

        int cur = 0;
        for (int kvb = 0; kvb <= qt; ++kvb) {
            // 2-phase: issue next tile's loads NOW; they fly during this tile's compute.
            if (kvb < qt) STAGE(cur ^ 1, kvb + 1);

            // S = Q K^T : this wave's 16 q-rows x 64 kv (exp2-domain, pre-scaled Q)
            f32x4 sacc[4];
            __builtin_amdgcn_s_setprio(1);
            #pragma unroll
            for (int kvt = 0; kvt < 4; ++kvt) {
                short8 k0v = *(const short8*)&Ks[cur][swz64(kvt * 16 + l15, l4 * 8)];
                short8 k1v = *(const short8*)&Ks[cur][swz64(kvt * 16 + l15, 32 + l4 * 8)];
                sacc[kvt] = (f32x4){0.f, 0.f, 0.f, 0.f};
                sacc[kvt] = __builtin_amdgcn_mfma_f32_16x16x32_bf16(qa0, k0v, sacc[kvt], 0, 0, 0);
                sacc[kvt] = __builtin_amdgcn_mfma_f32_16x16x32_bf16(qa1, k1v, sacc[kvt], 0, 0, 0);
            }
            __builtin_amdgcn_s_setprio(0);

            if (kvb == qt) {       // causal mask, diag tile only (uniform branch)
                #pragma unroll
                for (int kvt = 0; kvt < 4; ++kvt)
                    #pragma unroll
                    for (int r = 0; r < 4; ++r) {
                        int ql = w * 16 + l4 * 4 + r;
                        int kl = kvt * 16 + l15;
                        if (kl > ql) sacc[kvt][r] = -__builtin_inff();
                    }
            }

            // online softmax per q-row (row lives across the 16-lane l15 group),
            // exp2 domain; defer-max (T13): skip O-rescale when max growth small.
            #pragma unroll
            for (int r = 0; r < 4; ++r) {
                float tmax = fmaxf(fmaxf(sacc[0][r], sacc[1][r]), fmaxf(sacc[2][r], sacc[3][r]));
                tmax = fmaxf(tmax, __shfl_xor(tmax, 1));
                tmax = fmaxf(tmax, __shfl_xor(tmax, 2));
                tmax = fmaxf(tmax, __shfl_xor(tmax, 4));
                tmax = fmaxf(tmax, __shfl_xor(tmax, 8));
                bool skip = (tmax <= m[r] + DEFER_THR);    // uniform within 16-lane group
                float mn = skip ? m[r] : tmax;
                float rsum = 0.f;
                #pragma unroll
                for (int kvt = 0; kvt < 4; ++kvt) {
                    float p = exp2f(sacc[kvt][r] - mn);
                    sacc[kvt][r] = p;
                    rsum += p;
                }
                rsum += __shfl_xor(rsum, 1);
                rsum += __shfl_xor(rsum, 2);
                rsum += __shfl_xor(rsum, 4);
                rsum += __shfl_xor(rsum, 8);
                if (skip) {
                    ll[r] += rsum;
                } else {
                    float alpha = exp2f(m[r] - mn);
                    ll[r] = ll[r] * alpha + rsum;
                    m[r] = mn;
                    #pragma unroll
                    for (int dt = 0; dt < 4; ++dt) oacc[dt][r] *= alpha;
                }
            }

            // P -> per-wave LDS (swizzled) -> A-operand fragments
            #pragma unroll
            for (int kvt = 0; kvt < 4; ++kvt)
                #pragma unroll
                for (int r = 0; r < 4; ++r)
                    Ps[w * 1024 + swz64(l4 * 4 + r, kvt * 16 + l15)] = f2bf(sacc[kvt][r]);
            // same-wave DS ordering: compiler inserts lgkmcnt before dependent reads
            short8 pa0 = *(const short8*)&Ps[w * 1024 + swz64(l15, l4 * 8)];
            short8 pa1 = *(const short8*)&Ps[w * 1024 + swz64(l15, 32 + l4 * 8)];

            __builtin_amdgcn_s_setprio(1);
            #pragma unroll
            for (int dt = 0; dt < 4; ++dt) {
                short8 vb0 = *(const short8*)&Vs[cur][swz64(dt * 16 + l15, l4 * 8)];
                short8 vb1 = *(const short8*)&Vs[cur][swz64(dt * 16 + l15, 32 + l4 * 8)];
                oacc[dt] = __builtin_amdgcn_mfma_f32_16x16x32_bf16(pa0, vb0, oacc[dt], 0, 0, 0);
                oacc[dt] = __builtin_amdgcn_mfma_f32_16x16x32_bf16(pa1, vb1, oacc[dt], 0, 0, 0);
            }
            __builtin_amdgcn_s_setprio(0);

            // single barrier per iter: __syncthreads' vmcnt(0)+lgkmcnt(0) drain
            // completes the prefetched loads AND protects buf reuse.
            __syncthreads();
            cur ^= 1;
        }

        #pragma unroll
        for (int r = 0; r < 4; ++r) {
            float inv = 1.0f / ll[r];
            int row = qt * 64 + w * 16 + l4 * 4 + r;
            unsigned short* op = ao + ((size_t)b * 2048 + row) * 1024 + h * 64;
            #pragma unroll
            for (int dt = 0; dt < 4; ++dt)
                op[dt * 16 + l15] = f2bf(oacc[dt][r] * inv);
        }
    }
    #undef STAGE
}

// ---------------- launch ----------------
extern "C" void kernel_launch(void* const* d_in, const int* in_sizes, int n_in,
                              void* d_out, int out_size, void* d_ws, size_t ws_size,
                              hipStream_t stream) {
    const float* x    = (const float*)d_in[0];
    // d_in[1] = causal mask (deterministic tril) — applied analytically
    const float* Wqkv = (const float*)d_in[2];
    const float* Wo   = (const float*)d_in[3];
    const float* bo   = (const float*)d_in[4];
    float* out = (float*)d_out;

    char* ws = (char*)d_ws;
    unsigned short* xb    = (unsigned short*)(ws);               // [8192][1024] bf16, 16 MB
    unsigned short* wqkvt = (unsigned short*)(ws + 16777216);    // [3072][1024] bf16 (Wqkv^T), 6 MB
    unsigned short* wot   = (unsigned short*)(ws + 23068672);    // [1024][1024] bf16 (Wo^T), 2 MB
    unsigned short* qkb   = (unsigned short*)(ws + 25165824);    // [8192][2048] bf16 (q|k), 32 MB
    unsigned short* vtb   = (unsigned short*)(ws + 58720256);    // [1024][8192] bf16 (V^T), 16 MB
    unsigned short* ao    = (unsigned short*)(ws + 75497472);    // [8192][1024] bf16, 16 MB

    cvt_bf16<<<8192, 256, 0, stream>>>(x, xb, 8192 * 1024);
    transpose_cvt<<<dim3(96, 32), dim3(32, 8), 0, stream>>>(Wqkv, wqkvt, 1024, 3072);
    transpose_cvt<<<dim3(32, 32), dim3(32, 8), 0, stream>>>(Wo, wot, 1024, 1024);

    // QK projection: [8192][2048], q columns pre-scaled by 0.125*log2e
    gemm_bt<0, 1, 1><<<dim3(64, 16), 256, 0, stream>>>(xb, wqkvt, (void*)qkb, nullptr, 8192, 2048, 1024);
    // V^T projection: vt[d_global][token] = sum_k WqkvT[2048+d][k] * x[token][k]
    gemm_bt<0, 1, 0><<<dim3(8, 64), 256, 0, stream>>>(wqkvt + (size_t)2048 * 1024, xb, (void*)vtb, nullptr, 1024, 8192, 1024);

    flash_attn<<<dim3(1024), 256, 0, stream>>>(qkb, vtb, ao);

    gemm_bt<1, 0, 0><<<dim3(64, 8), 256, 0, stream>>>(ao, wot, (void*)out, bo, 8192, 1024, 1024);
}

// Round 9
// 318.533 us; speedup vs baseline: 1.4531x; 1.2421x over previous
//
#include <hip/hip_runtime.h>

typedef __attribute__((ext_vector_type(8))) short short8;
typedef __attribute__((ext_vector_type(4))) short short4v;
typedef __attribute__((ext_vector_type(4))) float f32x4;
typedef __attribute__((ext_vector_type(4))) unsigned short ushort4v;

#define QK_PRESCALE 0.18033688011112043f   /* 0.125 * log2(e): S comes out in exp2 domain */
#define DEFER_THR 11.5f                    /* ~8 nats in exp2 domain */

__device__ __forceinline__ unsigned short f2bf(float f) {
    union { float f; unsigned int u; } v; v.f = f;
    unsigned int r = v.u + 0x7FFFu + ((v.u >> 16) & 1u);
    return (unsigned short)(r >> 16);
}

// ---------------- fp32 -> bf16 elementwise ----------------
__global__ __launch_bounds__(256) void cvt_bf16(const float* __restrict__ in,
                                                unsigned short* __restrict__ out, int n) {
    int i = (blockIdx.x * 256 + threadIdx.x) * 4;
    if (i >= n) return;
    f32x4 v = *(const f32x4*)(in + i);
    ushort4v o;
    o[0] = f2bf(v[0]); o[1] = f2bf(v[1]); o[2] = f2bf(v[2]); o[3] = f2bf(v[3]);
    *(ushort4v*)(out + i) = o;
}

// ---------------- transpose + convert: W[K][N] -> WT[N][K] bf16 ----------------
__global__ __launch_bounds__(256) void transpose_cvt(const float* __restrict__ W,
                                                     unsigned short* __restrict__ WT,
                                                     int Kd, int Nd) {
    __shared__ float tile[32][33];
    int n0 = blockIdx.x * 32, k0 = blockIdx.y * 32;
    int tx = threadIdx.x, ty = threadIdx.y;
    #pragma unroll
    for (int i = 0; i < 4; ++i)
        tile[ty + i * 8][tx] = W[(size_t)(k0 + ty + i * 8) * Nd + n0 + tx];
    __syncthreads();
    #pragma unroll
    for (int i = 0; i < 4; ++i) {
        int r = ty + i * 8;
        WT[(size_t)(n0 + r) * Kd + k0 + tx] = f2bf(tile[tx][r]);
    }
}

// ---------------- GEMM: C[M][N] = A[M][K] * BT[N][K]^T  (m97 structure) ----------------
#define AS1U(p) ((const __attribute__((address_space(1))) unsigned int*)(p))
#define AS3U(p) ((__attribute__((address_space(3))) unsigned int*)(p))

template<int BIAS, int OUTBF16, int QSCALE>
__global__ __launch_bounds__(256) void gemm_bt(const unsigned short* __restrict__ A,
                                               const unsigned short* __restrict__ BT,
                                               void* __restrict__ Cv,
                                               const float* __restrict__ bias,
                                               int M, int N, int K) {
    __shared__ unsigned short As[128 * 32];
    __shared__ unsigned short Bs[128 * 32];
    int tid = threadIdx.x;
    int l = tid & 63, l15 = l & 15, l4 = l >> 4;
    int w = tid >> 6, wm = w >> 1, wn = w & 1;
    int bm = blockIdx.x, bn = blockIdx.y;

    f32x4 acc[4][4];
    #pragma unroll
    for (int mt = 0; mt < 4; ++mt)
        #pragma unroll
        for (int nt = 0; nt < 4; ++nt)
            acc[mt][nt] = (f32x4){0.f, 0.f, 0.f, 0.f};

    int srow = tid >> 2;             // 0..63
    int skk  = (tid & 3) * 8;        // 8-elem chunk within 32-wide K slab

    const unsigned short* Ab = A  + (size_t)(bm * 128) * K;
    const unsigned short* Bb = BT + (size_t)(bn * 128) * K;

    for (int kt = 0; kt < K; kt += 32) {
        __syncthreads();
        __builtin_amdgcn_global_load_lds(AS1U(Ab + (size_t)srow        * K + kt + skk), AS3U(&As[tid * 8]),         16, 0, 0);
        __builtin_amdgcn_global_load_lds(AS1U(Ab + (size_t)(srow + 64) * K + kt + skk), AS3U(&As[(256 + tid) * 8]), 16, 0, 0);
        __builtin_amdgcn_global_load_lds(AS1U(Bb + (size_t)srow        * K + kt + skk), AS3U(&Bs[tid * 8]),         16, 0, 0);
        __builtin_amdgcn_global_load_lds(AS1U(Bb + (size_t)(srow + 64) * K + kt + skk), AS3U(&Bs[(256 + tid) * 8]), 16, 0, 0);
        __syncthreads();

        short8 av[4], bv[4];
        #pragma unroll
        for (int mt = 0; mt < 4; ++mt)
            av[mt] = *(const short8*)&As[(wm * 64 + mt * 16 + l15) * 32 + l4 * 8];
        #pragma unroll
        for (int nt = 0; nt < 4; ++nt)
            bv[nt] = *(const short8*)&Bs[(wn * 64 + nt * 16 + l15) * 32 + l4 * 8];
        #pragma unroll
        for (int mt = 0; mt < 4; ++mt)
            #pragma unroll
            for (int nt = 0; nt < 4; ++nt)
                acc[mt][nt] = __builtin_amdgcn_mfma_f32_16x16x32_bf16(av[mt], bv[nt], acc[mt][nt], 0, 0, 0);
    }

    #pragma unroll
    for (int mt = 0; mt < 4; ++mt) {
        #pragma unroll
        for (int r = 0; r < 4; ++r) {
            int row = bm * 128 + wm * 64 + mt * 16 + l4 * 4 + r;
            #pragma unroll
            for (int nt = 0; nt < 4; ++nt) {
                int col = bn * 128 + wn * 64 + nt * 16 + l15;
                float vv = acc[mt][nt][r];
                if (BIAS) vv += bias[col];
                if (QSCALE && col < 1024) vv *= QK_PRESCALE;   // q columns only
                if (OUTBF16) ((unsigned short*)Cv)[(size_t)row * N + col] = f2bf(vv);
                else         ((float*)Cv)[(size_t)row * N + col] = vv;
            }
        }
    }
}

// ---------------- flash attention (causal) ----------------
// qk: [B*T][2048] bf16 (q|k each 1024, head h at h*64; q pre-scaled by 0.125*log2e)
// vt: [1024][B*T]  bf16 (V pre-transposed: row = h*64+d, col = b*2048+t)
// ao: [B*T][1024] bf16
__device__ __forceinline__ int swz64(int row, int e) {
    return row * 64 + (e ^ ((row & 7) << 3));     // XOR-swizzle 8-elem chunks in a 128B row
}

__global__ __launch_bounds__(256) void flash_attn(const unsigned short* __restrict__ qk,
                                                  const unsigned short* __restrict__ vt,
                                                  unsigned short* __restrict__ ao) {
    // XCD-aware bijective remap (nwg=1024, 8 XCDs, cpx=128): each XCD owns 8
    // consecutive bh values -> that XCD's L2 holds their K/V (8 * 512KB = 4MB).
    int nid = (blockIdx.x & 7) * 128 + (blockIdx.x >> 3);
    int pr = nid & 15;                // pairs q-tiles (pr, 31-pr): uniform 33 iters
    int bh = nid >> 4;                // 0..63
    int b = bh >> 4, h = bh & 15;
    int tid = threadIdx.x;
    int w = tid >> 6, l = tid & 63, l15 = l & 15, l4 = l >> 4;

    __shared__ unsigned short Ks[2][4096];   // K tile  [kv=64][d=64]  swizzled, dbuf
    __shared__ unsigned short Vs[2][4096];   // V^T tile [d=64][kv=64] swizzled, dbuf
    __shared__ unsigned short Ps[4096];      // per-wave P [16][64]    swizzled

    const size_t qkbase = (size_t)b * 2048 * 2048;

    // Staging geometry: wave w writes chunks w*128 + j*64 + lane (16B each).
    // LDS dest linear (wave-uniform base + lane*16); global source pre-swizzled
    // per-lane so the LDS image matches swz64 layout.
    int c0i = w * 128 + l;
    int row0 = c0i >> 3, sub0 = c0i & 7;
    int c1i = c0i + 64;
    int row1 = c1i >> 3, sub1 = c1i & 7;

    const unsigned short* Kp0b = qk + qkbase + 1024 + h * 64 + (size_t)row0 * 2048 + 8 * (sub0 ^ (row0 & 7));
    const unsigned short* Kp1b = qk + qkbase + 1024 + h * 64 + (size_t)row1 * 2048 + 8 * (sub1 ^ (row1 & 7));
    const unsigned short* Vp0b = vt + (size_t)(h * 64 + row0) * 8192 + (size_t)b * 2048 + 8 * (sub0 ^ (row0 & 7));
    const unsigned short* Vp1b = vt + (size_t)(h * 64 + row1) * 8192 + (size_t)b * 2048 + 8 * (sub1 ^ (row1 & 7));

    #define STAGE(buf, kvb_)                                                                        \
        do {                                                                                        \
            size_t koff = (size_t)(kvb_) * (64 * 2048);                                             \
            int    voff = (kvb_) * 64;                                                              \
            __builtin_amdgcn_global_load_lds(AS1U(Kp0b + koff), AS3U(&Ks[buf][w * 1024]),       16, 0, 0); \
            __builtin_amdgcn_global_load_lds(AS1U(Kp1b + koff), AS3U(&Ks[buf][w * 1024 + 512]), 16, 0, 0); \
            __builtin_amdgcn_global_load_lds(AS1U(Vp0b + voff), AS3U(&Vs[buf][w * 1024]),       16, 0, 0); \
            __builtin_amdgcn_global_load_lds(AS1U(Vp1b + voff), AS3U(&Vs[buf][w * 1024 + 512]), 16, 0, 0); \
        } while (0)

    #pragma unroll
    for (int t = 0; t < 2; ++t) {
        int qt = t ? (31 - pr) : pr;

        int qrow = qt * 64 + w * 16 + l15;
        const unsigned short* qp = qk + qkbase + (size_t)qrow * 2048 + h * 64 + l4 * 8;
        short8 qa0 = *(const short8*)(qp);
        short8 qa1 = *(const short8*)(qp + 32);

        // swapped-operand state: each lane owns q-row (w*16 + l15), replicated
        // across the 4 l4-groups. m/ll are per-lane scalars now.
        float mrow = -__builtin_inff(), llrow = 0.f;
        f32x4 oacc[4];   // O[q = w*16 + l4*4 + r][d = dt*16 + l15]
        #pragma unroll
        for (int dt = 0; dt < 4; ++dt) oacc[dt] = (f32x4){0.f, 0.f, 0.f, 0.f};

        STAGE(0, 0);
        __syncthreads();           // drain prologue loads (vmcnt(0) before s_barrier)

        int cur = 0;
        for (int kvb = 0; kvb <= qt; ++kvb) {
            // 2-phase: issue next tile's loads NOW; they fly during this tile's compute.
            if (kvb < qt) STAGE(cur ^ 1, kvb + 1);

            // S = (K Q^T) swapped: sacc[kvt][r] = S[q = w*16+l15][kv = kvt*16 + l4*4 + r]
            // -> full P-row is lane-local: row-reduce = in-lane chain + 2 shfls.
            f32x4 sacc[4];
            __builtin_amdgcn_s_setprio(1);
            #pragma unroll
            for (int kvt = 0; kvt < 4; ++kvt) {
                short8 k0v = *(const short8*)&Ks[cur][swz64(kvt * 16 + l15, l4 * 8)];
                short8 k1v = *(const short8*)&Ks[cur][swz64(kvt * 16 + l15, 32 + l4 * 8)];
                sacc[kvt] = (f32x4){0.f, 0.f, 0.f, 0.f};
                sacc[kvt] = __builtin_amdgcn_mfma_f32_16x16x32_bf16(k0v, qa0, sacc[kvt], 0, 0, 0);
                sacc[kvt] = __builtin_amdgcn_mfma_f32_16x16x32_bf16(k1v, qa1, sacc[kvt], 0, 0, 0);
            }
            __builtin_amdgcn_s_setprio(0);

            if (kvb == qt) {       // causal mask, diag tile only (uniform branch)
                int ql = w * 16 + l15;
                #pragma unroll
                for (int kvt = 0; kvt < 4; ++kvt)
                    #pragma unroll
                    for (int r = 0; r < 4; ++r) {
                        int kl = kvt * 16 + l4 * 4 + r;
                        if (kl > ql) sacc[kvt][r] = -__builtin_inff();
                    }
            }

            // online softmax: in-lane max/sum over 16 kv + 2 shfls across l4 groups.
            float tmax = sacc[0][0];
            #pragma unroll
            for (int kvt = 0; kvt < 4; ++kvt)
                #pragma unroll
                for (int r = 0; r < 4; ++r)
                    tmax = fmaxf(tmax, sacc[kvt][r]);
            tmax = fmaxf(tmax, __shfl_xor(tmax, 16));
            tmax = fmaxf(tmax, __shfl_xor(tmax, 32));

            bool skip = (tmax <= mrow + DEFER_THR);    // uniform across a row's 4 lanes
            float mn = skip ? mrow : tmax;
            float alphaL = skip ? 1.f : exp2f(mrow - mn);

            float rsum = 0.f;
            #pragma unroll
            for (int kvt = 0; kvt < 4; ++kvt)
                #pragma unroll
                for (int r = 0; r < 4; ++r) {
                    float p = exp2f(sacc[kvt][r] - mn);
                    sacc[kvt][r] = p;
                    rsum += p;
                }
            rsum += __shfl_xor(rsum, 16);
            rsum += __shfl_xor(rsum, 32);

            llrow = llrow * alphaL + rsum;
            mrow = mn;

            // O-rescale: alpha lives in q-row space (l15); O rows are l4*4+r.
            // Broadcast via 4 lane-gathers, only when some row actually rescales.
            if (__any(!skip)) {
                #pragma unroll
                for (int r = 0; r < 4; ++r) {
                    float aO = __shfl(alphaL, l4 * 4 + r);   // lanes 0-15 hold rows 0-15
                    #pragma unroll
                    for (int dt = 0; dt < 4; ++dt) oacc[dt][r] *= aO;
                }
            }

            // P -> per-wave LDS: 4 x ds_write_b64 (4 consecutive kv per kvt), swizzled.
            #pragma unroll
            for (int kvt = 0; kvt < 4; ++kvt) {
                short4v pk;
                pk[0] = (short)f2bf(sacc[kvt][0]);
                pk[1] = (short)f2bf(sacc[kvt][1]);
                pk[2] = (short)f2bf(sacc[kvt][2]);
                pk[3] = (short)f2bf(sacc[kvt][3]);
                *(short4v*)&Ps[w * 1024 + swz64(l15, kvt * 16 + l4 * 4)] = pk;
            }
            // same-wave DS ordering: compiler inserts lgkmcnt before dependent reads
            short8 pa0 = *(const short8*)&Ps[w * 1024 + swz64(l15, l4 * 8)];
            short8 pa1 = *(const short8*)&Ps[w * 1024 + swz64(l15, 32 + l4 * 8)];

            __builtin_amdgcn_s_setprio(1);
            #pragma unroll
            for (int dt = 0; dt < 4; ++dt) {
                short8 vb0 = *(const short8*)&Vs[cur][swz64(dt * 16 + l15, l4 * 8)];
                short8 vb1 = *(const short8*)&Vs[cur][swz64(dt * 16 + l15, 32 + l4 * 8)];
                oacc[dt] = __builtin_amdgcn_mfma_f32_16x16x32_bf16(pa0, vb0, oacc[dt], 0, 0, 0);
                oacc[dt] = __builtin_amdgcn_mfma_f32_16x16x32_bf16(pa1, vb1, oacc[dt], 0, 0, 0);
            }
            __builtin_amdgcn_s_setprio(0);

            // single barrier per iter: __syncthreads' vmcnt(0)+lgkmcnt(0) drain
            // completes the prefetched loads AND protects buf reuse.
            __syncthreads();
            cur ^= 1;
        }

        #pragma unroll
        for (int r = 0; r < 4; ++r) {
            float llO = __shfl(llrow, l4 * 4 + r);     // ll for O-row l4*4+r
            float inv = 1.0f / llO;
            int row = qt * 64 + w * 16 + l4 * 4 + r;
            unsigned short* op = ao + ((size_t)b * 2048 + row) * 1024 + h * 64;
            #pragma unroll
            for (int dt = 0; dt < 4; ++dt)
                op[dt * 16 + l15] = f2bf(oacc[dt][r] * inv);
        }
    }
    #undef STAGE
}

// ---------------- launch ----------------
extern "C" void kernel_launch(void* const* d_in, const int* in_sizes, int n_in,
                              void* d_out, int out_size, void* d_ws, size_t ws_size,
                              hipStream_t stream) {
    const float* x    = (const float*)d_in[0];
    // d_in[1] = causal mask (deterministic tril) — applied analytically
    const float* Wqkv = (const float*)d_in[2];
    const float* Wo   = (const float*)d_in[3];
    const float* bo   = (const float*)d_in[4];
    float* out = (float*)d_out;

    char* ws = (char*)d_ws;
    unsigned short* xb    = (unsigned short*)(ws);               // [8192][1024] bf16, 16 MB
    unsigned short* wqkvt = (unsigned short*)(ws + 16777216);    // [3072][1024] bf16 (Wqkv^T), 6 MB
    unsigned short* wot   = (unsigned short*)(ws + 23068672);    // [1024][1024] bf16 (Wo^T), 2 MB
    unsigned short* qkb   = (unsigned short*)(ws + 25165824);    // [8192][2048] bf16 (q|k), 32 MB
    unsigned short* vtb   = (unsigned short*)(ws + 58720256);    // [1024][8192] bf16 (V^T), 16 MB
    unsigned short* ao    = (unsigned short*)(ws + 75497472);    // [8192][1024] bf16, 16 MB

    cvt_bf16<<<8192, 256, 0, stream>>>(x, xb, 8192 * 1024);
    transpose_cvt<<<dim3(96, 32), dim3(32, 8), 0, stream>>>(Wqkv, wqkvt, 1024, 3072);
    transpose_cvt<<<dim3(32, 32), dim3(32, 8), 0, stream>>>(Wo, wot, 1024, 1024);

    // QK projection: [8192][2048], q columns pre-scaled by 0.125*log2e
    gemm_bt<0, 1, 1><<<dim3(64, 16), 256, 0, stream>>>(xb, wqkvt, (void*)qkb, nullptr, 8192, 2048, 1024);
    // V^T projection: vt[d_global][token] = sum_k WqkvT[2048+d][k] * x[token][k]
    gemm_bt<0, 1, 0><<<dim3(8, 64), 256, 0, stream>>>(wqkvt + (size_t)2048 * 1024, xb, (void*)vtb, nullptr, 1024, 8192, 1024);

    flash_attn<<<dim3(1024), 256, 0, stream>>>(qkb, vtb, ao);

    gemm_bt<1, 0, 0><<<dim3(64, 8), 256, 0, stream>>>(ao, wot, (void*)out, bo, 8192, 1024, 1024);
}